// Round 22
// baseline (175.425 us; speedup 1.0000x reference)
//
#include <hip/hip_runtime.h>

#define N_NODES 4096
#define N_EDGES 262144
#define EPS 1e-5f
#define CAP 192

// workspace offsets (float units)
#define O_CTXT 0        // ctx^T f32 [128][4096]
#define O_BASE 524288   // base [4096][128]
#define O_XSA  1048576
#define O_XTB  1310720
#define O_TAB  1572864  // 33 regions x 320
#define O_AUX  1583424  // thr[32] + R0[64]
#define O_RECS 1583552  // float4 [4096][CAP]
#define O_RECT 4729280  // float2 [4096][CAP]
#define O_CNTS 6826432
#define O_CNTT 6830528
#define O_QB   6838720  // bf16 [4][4096][32]
#define O_KB   7100864
#define O_VT   7363008  // bf16 [4][32][4096]
#define O_WT   7625152  // transposed weights
#define O_CMB  7788992  // comb [4096][192]
// within WT:
#define T_INP  0
#define T_WQ   16384
#define T_WK   32768
#define T_WV   49152
#define T_AW   65536
#define T_OW   81920
#define T_SC   98304
#define T_AGG  114688   // [192][256]

typedef __attribute__((ext_vector_type(8))) short short8v;
typedef __attribute__((ext_vector_type(4))) float f32x4;

__device__ __forceinline__ ushort f2bf(float x) {
    uint u = __builtin_bit_cast(uint, x);
    uint r = (u + 0x7FFFu + ((u >> 16) & 1u)) >> 16;
    return (ushort)r;
}
__device__ __forceinline__ float fexp2(float x) { return __builtin_amdgcn_exp2f(x); }

// ---------------- K-1: one-time weight transposes + counter zeroing ----------------
__global__ __launch_bounds__(256) void k_tr(
    const float* __restrict__ inp_w, const float* __restrict__ wq,
    const float* __restrict__ wk, const float* __restrict__ wv,
    const float* __restrict__ aw, const float* __restrict__ ow,
    const float* __restrict__ sc_w1, const float* __restrict__ agg_w,
    float* __restrict__ wt, float* __restrict__ zbuf)
{
    int idx = blockIdx.x*256 + threadIdx.x;
    if (idx < 8192) zbuf[idx] = 0.f;   // cnt_s, cnt_t (contiguous)
    if (idx < 114688) {
        int m = idx >> 14;
        int r = idx & 16383;
        int i = r >> 7, c = r & 127;
        float v;
        switch (m) {
            case 0: v = inp_w[c*128+i]; break;
            case 1: v = wq[c*128+i]; break;
            case 2: v = wk[c*128+i]; break;
            case 3: v = wv[c*128+i]; break;
            case 4: v = aw[c*128+i]; break;
            case 5: v = ow[c*128+i]; break;
            default: v = (c < 64) ? sc_w1[c*320+i] : sc_w1[(c-64)*320+128+i]; break;
        }
        wt[idx] = v;
    } else {
        int a = idx - 114688;
        int i = a >> 8, c = a & 255;
        wt[idx] = agg_w[c*192 + i];
    }
}

// ---------------- K0: region tables for piecewise-linear temporal MLP ----------------
__global__ __launch_bounds__(64) void k_setup(
    const float* __restrict__ te_w1, const float* __restrict__ te_b1,
    const float* __restrict__ te_w2, const float* __restrict__ te_b2,
    const float* __restrict__ ln_g, const float* __restrict__ ln_b,
    const float* __restrict__ sc_w1, float* __restrict__ tab, float* __restrict__ aux)
{
    __shared__ float t_s[32];
    __shared__ int pos_s[32];
    __shared__ float AG_s[64], BG_s[64];
    int r = blockIdx.x;
    int c = threadIdx.x;
    if (c < 32) {
        float w = te_w1[c], b = te_b1[c];
        t_s[c] = (w != 0.f) ? (-b / w) : 1e30f;
    }
    __syncthreads();
    if (c < 32) {
        float t = t_s[c];
        int p = 0;
        for (int i = 0; i < 32; i++) {
            float ti = t_s[i];
            p += (ti < t) || (ti == t && i < c);
        }
        pos_s[c] = p;
    }
    __syncthreads();
    float A = 0.f, B = te_b2[c];
    for (int j = 0; j < 32; j++) {
        float w = te_w1[j], b = te_b1[j];
        bool act = (w > 0.f) ? (pos_s[j] < r) : ((w < 0.f) ? (pos_s[j] >= r) : (b > 0.f));
        if (act) { float w2 = te_w2[c*32 + j]; A += w * w2; B += b * w2; }
    }
    float mA = A, mB = B;
    #pragma unroll
    for (int m = 32; m >= 1; m >>= 1) { mA += __shfl_xor(mA, m, 64); mB += __shfl_xor(mB, m, 64); }
    mA *= (1.f/64.f); mB *= (1.f/64.f);
    float a = A - mA, bq = B - mB;
    float qa = a*a, qb = a*bq, qc = bq*bq;
    #pragma unroll
    for (int m = 32; m >= 1; m >>= 1) {
        qa += __shfl_xor(qa, m, 64); qb += __shfl_xor(qb, m, 64); qc += __shfl_xor(qc, m, 64);
    }
    qa *= (1.f/64.f); qb *= (2.f/64.f); qc *= (1.f/64.f);
    float g = ln_g[c];
    float AG = a*g, BG = bq*g;
    AG_s[c] = AG; BG_s[c] = BG;
    float* row = tab + r*320;
    row[c] = AG; row[64+c] = BG;
    if (c == 0) { row[256] = qa; row[257] = qb; row[258] = qc; }
    __syncthreads();
    const float* wc = sc_w1 + c*320 + 256;
    float P = 0.f, Q = 0.f;
    for (int j = 0; j < 64; j++) { float w = wc[j]; P += AG_s[j]*w; Q += BG_s[j]*w; }
    row[128+c] = P; row[192+c] = Q;
    if (r == 0) {
        if (c < 32) aux[pos_s[c]] = t_s[c];
        float R0 = 0.f;
        for (int j = 0; j < 64; j++) R0 += ln_b[j] * wc[j];
        aux[32 + c] = R0;
    }
}

// ---------------- K1: projections + sc partials, 4 nodes/block, split-K x2 ----------------
__global__ __launch_bounds__(256) void k_proj_qkv(
    const float* __restrict__ x, const float* __restrict__ wt,
    const float* __restrict__ inp_b,
    const float* __restrict__ bq, const float* __restrict__ bk, const float* __restrict__ bv,
    ushort* __restrict__ qb, ushort* __restrict__ kbuf, ushort* __restrict__ vt,
    float* __restrict__ xsa, float* __restrict__ xtb)
{
    __shared__ float xs[512];
    __shared__ float xps[4][128];
    __shared__ float scrA[2][4][128];
    __shared__ float scrB[2][4][128];
    __shared__ float scrC[2][4][128];
    int tid = threadIdx.x;
    int c = tid & 127, hf = tid >> 7;
    int n0 = blockIdx.x*4;
    for (int i = tid; i < 512; i += 256) xs[i] = x[n0*128 + i];
    __syncthreads();
    int i0 = hf*64;
    const float* inpT = wt + T_INP;
    const float* scT  = wt + T_SC;
    {
        float a0=0,a1=0,a2=0,a3=0, s0=0,s1=0,s2=0,s3=0;
        #pragma unroll 4
        for (int i = 0; i < 64; i++) {
            int ii = i0 + i;
            float w  = inpT[ii*128 + c];
            float ws = scT[ii*128 + c];
            float x0 = xs[ii], x1 = xs[128+ii], x2 = xs[256+ii], x3 = xs[384+ii];
            a0=fmaf(x0,w,a0); a1=fmaf(x1,w,a1); a2=fmaf(x2,w,a2); a3=fmaf(x3,w,a3);
            s0=fmaf(x0,ws,s0); s1=fmaf(x1,ws,s1); s2=fmaf(x2,ws,s2); s3=fmaf(x3,ws,s3);
        }
        scrA[hf][0][c]=a0; scrA[hf][1][c]=a1; scrA[hf][2][c]=a2; scrA[hf][3][c]=a3;
        scrB[hf][0][c]=s0; scrB[hf][1][c]=s1; scrB[hf][2][c]=s2; scrB[hf][3][c]=s3;
    }
    __syncthreads();
    if (hf == 0) {
        float ib = inp_b[c];
        #pragma unroll
        for (int j = 0; j < 4; j++) xps[j][c] = scrA[0][j][c] + scrA[1][j][c] + ib;
    } else {
        #pragma unroll
        for (int j = 0; j < 4; j++) {
            float sv = scrB[0][j][c] + scrB[1][j][c];
            int n = n0 + j;
            if (c < 64) xsa[n*64+c] = sv; else xtb[n*64+(c-64)] = sv;
        }
    }
    __syncthreads();
    const float* wqT = wt + T_WQ;
    const float* wkT = wt + T_WK;
    const float* wvT = wt + T_WV;
    {
        float q0=0,q1=0,q2=0,q3=0,k0=0,k1=0,k2=0,k3=0,v0=0,v1=0,v2=0,v3=0;
        #pragma unroll 2
        for (int i = 0; i < 64; i++) {
            int ii = i0 + i;
            float wQ = wqT[ii*128 + c], wK = wkT[ii*128 + c], wV = wvT[ii*128 + c];
            float x0 = xps[0][ii], x1 = xps[1][ii], x2 = xps[2][ii], x3 = xps[3][ii];
            q0=fmaf(x0,wQ,q0); q1=fmaf(x1,wQ,q1); q2=fmaf(x2,wQ,q2); q3=fmaf(x3,wQ,q3);
            k0=fmaf(x0,wK,k0); k1=fmaf(x1,wK,k1); k2=fmaf(x2,wK,k2); k3=fmaf(x3,wK,k3);
            v0=fmaf(x0,wV,v0); v1=fmaf(x1,wV,v1); v2=fmaf(x2,wV,v2); v3=fmaf(x3,wV,v3);
        }
        scrA[hf][0][c]=q0; scrA[hf][1][c]=q1; scrA[hf][2][c]=q2; scrA[hf][3][c]=q3;
        scrB[hf][0][c]=k0; scrB[hf][1][c]=k1; scrB[hf][2][c]=k2; scrB[hf][3][c]=k3;
        scrC[hf][0][c]=v0; scrC[hf][1][c]=v1; scrC[hf][2][c]=v2; scrC[hf][3][c]=v3;
    }
    __syncthreads();
    const float QSCALE = 0.17677669529663687f * 1.4426950408889634f;
    int h = c >> 5, d = c & 31;
    if (hf == 0) {
        float bqc = bq[c], bkc = bk[c];
        #pragma unroll
        for (int j = 0; j < 4; j++) {
            int n = n0 + j;
            int qi = h*131072 + n*32 + d;
            float qv = scrA[0][j][c] + scrA[1][j][c] + bqc;
            float kv = scrB[0][j][c] + scrB[1][j][c] + bkc;
            qb[qi]   = f2bf(qv * QSCALE);
            kbuf[qi] = f2bf(kv);
        }
    } else {
        float bvc = bv[c];
        #pragma unroll
        for (int j = 0; j < 4; j++) {
            int n = n0 + j;
            float vv = scrC[0][j][c] + scrC[1][j][c] + bvc;
            vt[c*4096 + n] = f2bf(vv);
        }
    }
}

// ---------------- K2+K6 FUSED: dual-role kernel (attn blocks + edge blocks) ----------------
// grid 4608 x 512. blockIdx%9==0 -> attention (bxa = blockIdx/9, 512 blocks);
// else -> edge (bxe = blockIdx - blockIdx/9 - 1 in [0,4096), 64 edges/block,
// single iteration). Finer edge granularity smooths the scheduling tail so
// attn MFMA work covers edge-atomic stalls throughout execution.
__global__ __launch_bounds__(512) void k_ea(
    const ushort* __restrict__ qb, const ushort* __restrict__ kb,
    const ushort* __restrict__ vt, float* __restrict__ ctxT,
    const int* __restrict__ eidx, const float* __restrict__ etime,
    const float* __restrict__ eattr,
    const float* __restrict__ tab, const float* __restrict__ aux,
    const float* __restrict__ sc_b1, const float* __restrict__ sc_w2,
    const float* __restrict__ sc_b2, const float* __restrict__ decay_p,
    const float* __restrict__ xsa, const float* __restrict__ xtb,
    int* __restrict__ cnt_s, int* __restrict__ cnt_t,
    float4* __restrict__ recS, float2* __restrict__ recT)
{
    __shared__ float smem[4608];   // 18432 B arena
    int tid = threadIdx.x;
    int lane = tid & 63;
    int wv = tid >> 6;
    int bm = blockIdx.x % 9;
    if (bm == 0) {
        // ================= ATTENTION ROLE =================
        float* lw0  = smem;            // [8][16]
        float* lw1  = smem + 128;      // [8][16]
        float* obuf = smem + 256;      // [8][512]
        int bxa = blockIdx.x / 9;
        int h = bxa & 3;
        int qg = bxa >> 2;
        int q15 = lane & 15;
        int g = lane >> 4;
        const ushort* qhb = qb + h*131072;
        const ushort* khb = kb + h*131072;
        const ushort* vhb = vt + h*131072;
        short8v qf0 = *(const short8v*)(qhb + (qg*32 + q15)*32 + g*8);
        short8v qf1 = *(const short8v*)(qhb + (qg*32 + 16 + q15)*32 + g*8);
        int key0off = ((q15 >> 2) << 3) + (q15 & 3);
        const f32x4 z = {0.f,0.f,0.f,0.f};
        f32x4 o0a = z, o1a = z, o0b = z, o1b = z;
        float lsum0 = 0.f, lsum1 = 0.f;
        int kstart = wv * 512;
        #pragma unroll 2
        for (int k32 = kstart; k32 < kstart + 512; k32 += 32) {
            short8v kf0 = *(const short8v*)(khb + (k32 + key0off)*32 + g*8);
            short8v kf1 = *(const short8v*)(khb + (k32 + key0off + 4)*32 + g*8);
            short8v vf0 = *(const short8v*)(vhb + q15*4096 + k32 + g*8);
            short8v vf1 = *(const short8v*)(vhb + (16 + q15)*4096 + k32 + g*8);
            f32x4 s0a = __builtin_amdgcn_mfma_f32_16x16x32_bf16(kf0, qf0, z, 0, 0, 0);
            f32x4 s1a = __builtin_amdgcn_mfma_f32_16x16x32_bf16(kf1, qf0, z, 0, 0, 0);
            f32x4 s0b = __builtin_amdgcn_mfma_f32_16x16x32_bf16(kf0, qf1, z, 0, 0, 0);
            f32x4 s1b = __builtin_amdgcn_mfma_f32_16x16x32_bf16(kf1, qf1, z, 0, 0, 0);
            float p0 = fexp2(s0a[0]), p1 = fexp2(s0a[1]);
            float p2 = fexp2(s0a[2]), p3 = fexp2(s0a[3]);
            float p4 = fexp2(s1a[0]), p5 = fexp2(s1a[1]);
            float p6 = fexp2(s1a[2]), p7 = fexp2(s1a[3]);
            lsum0 += ((p0 + p1) + (p2 + p3)) + ((p4 + p5) + (p6 + p7));
            short8v pfa;
            pfa[0] = (short)f2bf(p0); pfa[1] = (short)f2bf(p1);
            pfa[2] = (short)f2bf(p2); pfa[3] = (short)f2bf(p3);
            pfa[4] = (short)f2bf(p4); pfa[5] = (short)f2bf(p5);
            pfa[6] = (short)f2bf(p6); pfa[7] = (short)f2bf(p7);
            float r0 = fexp2(s0b[0]), r1 = fexp2(s0b[1]);
            float r2 = fexp2(s0b[2]), r3 = fexp2(s0b[3]);
            float r4 = fexp2(s1b[0]), r5 = fexp2(s1b[1]);
            float r6 = fexp2(s1b[2]), r7 = fexp2(s1b[3]);
            lsum1 += ((r0 + r1) + (r2 + r3)) + ((r4 + r5) + (r6 + r7));
            short8v pfb;
            pfb[0] = (short)f2bf(r0); pfb[1] = (short)f2bf(r1);
            pfb[2] = (short)f2bf(r2); pfb[3] = (short)f2bf(r3);
            pfb[4] = (short)f2bf(r4); pfb[5] = (short)f2bf(r5);
            pfb[6] = (short)f2bf(r6); pfb[7] = (short)f2bf(r7);
            o0a = __builtin_amdgcn_mfma_f32_16x16x32_bf16(vf0, pfa, o0a, 0, 0, 0);
            o1a = __builtin_amdgcn_mfma_f32_16x16x32_bf16(vf1, pfa, o1a, 0, 0, 0);
            o0b = __builtin_amdgcn_mfma_f32_16x16x32_bf16(vf0, pfb, o0b, 0, 0, 0);
            o1b = __builtin_amdgcn_mfma_f32_16x16x32_bf16(vf1, pfb, o1b, 0, 0, 0);
        }
        lsum0 += __shfl_xor(lsum0, 16, 64);
        lsum0 += __shfl_xor(lsum0, 32, 64);
        lsum1 += __shfl_xor(lsum1, 16, 64);
        lsum1 += __shfl_xor(lsum1, 32, 64);
        if (lane < 16) { lw0[wv*16 + lane] = lsum0; lw1[wv*16 + lane] = lsum1; }
        #pragma unroll
        for (int r = 0; r < 4; r++) {
            obuf[wv*512 + r*64 + lane]       = o0a[r];
            obuf[wv*512 + (4 + r)*64 + lane] = o1a[r];
        }
        __syncthreads();
        {
            int e = tid;
            int lp = e & 63, r8 = e >> 6;
            int q = lp & 15;
            float L = ((lw0[0*16+q]+lw0[1*16+q]) + (lw0[2*16+q]+lw0[3*16+q]))
                    + ((lw0[4*16+q]+lw0[5*16+q]) + (lw0[6*16+q]+lw0[7*16+q]));
            float a = ((obuf[0*512+e]+obuf[1*512+e]) + (obuf[2*512+e]+obuf[3*512+e]))
                    + ((obuf[4*512+e]+obuf[5*512+e]) + (obuf[6*512+e]+obuf[7*512+e]));
            int d = ((lp >> 4) << 2) + (r8 & 3) + ((r8 >> 2) << 4);
            ctxT[(h*32 + d)*4096 + qg*32 + q] = a / L;
        }
        __syncthreads();
        #pragma unroll
        for (int r = 0; r < 4; r++) {
            obuf[wv*512 + r*64 + lane]       = o0b[r];
            obuf[wv*512 + (4 + r)*64 + lane] = o1b[r];
        }
        __syncthreads();
        {
            int e = tid;
            int lp = e & 63, r8 = e >> 6;
            int q = lp & 15;
            float L = ((lw1[0*16+q]+lw1[1*16+q]) + (lw1[2*16+q]+lw1[3*16+q]))
                    + ((lw1[4*16+q]+lw1[5*16+q]) + (lw1[6*16+q]+lw1[7*16+q]));
            float a = ((obuf[0*512+e]+obuf[1*512+e]) + (obuf[2*512+e]+obuf[3*512+e]))
                    + ((obuf[4*512+e]+obuf[5*512+e]) + (obuf[6*512+e]+obuf[7*512+e]));
            int d = ((lp >> 4) << 2) + (r8 & 3) + ((r8 >> 2) << 4);
            ctxT[(h*32 + d)*4096 + qg*32 + 16 + q] = a / L;
        }
    } else {
        // ================= EDGE ROLE (64 edges, single iteration) =================
        float* pq    = smem;            // [33*128]
        float* qpoly = smem + 4224;     // [33*4]
        float* thrL  = smem + 4356;     // [32]
        float* u0L   = smem + 4388;     // [64]
        float* sw2L  = smem + 4452;     // [64]
        int bxe = blockIdx.x - blockIdx.x/9 - 1;
        for (int i = tid; i < 33*128; i += 512)
            pq[i] = tab[(i >> 7)*320 + 128 + (i & 127)];
        if (tid < 33) {
            qpoly[tid*4+0] = tab[tid*320+256];
            qpoly[tid*4+1] = tab[tid*320+257];
            qpoly[tid*4+2] = tab[tid*320+258];
        }
        if (tid < 32) thrL[tid] = aux[tid];
        if (tid < 64) { u0L[tid] = sc_b1[tid] + aux[32+tid]; sw2L[tid] = sc_w2[tid]; }
        __syncthreads();
        float decay = decay_p[0];
        float sb2 = sc_b2[0];
        int g = lane >> 4, q = lane & 15;
        float th1 = thrL[q], th2 = thrL[16 + q];
        float4 u4 = *(const float4*)&u0L[q*4];
        float4 w4 = *(const float4*)&sw2L[q*4];
        {
            int base_e = bxe*64;
            int eA = base_e + wv*8 + g;
            int eB = eA + 4;
            int srcA = eidx[eA], tgtA = eidx[N_EDGES + eA];
            int srcB = eidx[eB], tgtB = eidx[N_EDGES + eB];
            float tA = etime[eA], tB = etime[eB];
            float hier = 0.f, tfj = 0.f;
            int sl = 0, pt = 0;
            if (q == 0) {
                sl = atomicAdd(&cnt_s[srcA], 1);
                pt = atomicAdd(&cnt_t[tgtA], 1);
                hier = eattr[eA*17 + 16]; tfj = eattr[eA*17 + 5];
            } else if (q == 1) {
                sl = atomicAdd(&cnt_s[srcB], 1);
                pt = atomicAdd(&cnt_t[tgtB], 1);
                hier = eattr[eB*17 + 16]; tfj = eattr[eB*17 + 5];
            }
            float wtA = tA * __expf(-fabsf(tA)*decay);
            float wtB = tB * __expf(-fabsf(tB)*decay);
            unsigned long long bA1 = __ballot(wtA > th1);
            unsigned long long bA2 = __ballot(wtA > th2);
            unsigned long long bB1 = __ballot(wtB > th1);
            unsigned long long bB2 = __ballot(wtB > th2);
            int sh = g*16;
            int rA = __popc((uint)((bA1 >> sh) & 0xFFFF)) + __popc((uint)((bA2 >> sh) & 0xFFFF));
            int rB = __popc((uint)((bB1 >> sh) & 0xFFFF)) + __popc((uint)((bB2 >> sh) & 0xFFFF));
            float4 xaA = *(const float4*)&xsa[srcA*64 + q*4];
            float4 xbA = *(const float4*)&xtb[tgtA*64 + q*4];
            float4 xaB = *(const float4*)&xsa[srcB*64 + q*4];
            float4 xbB = *(const float4*)&xtb[tgtB*64 + q*4];
            float4 PA = *(const float4*)&pq[rA*128 + q*4];
            float4 QA = *(const float4*)&pq[rA*128 + 64 + q*4];
            float4 PB = *(const float4*)&pq[rB*128 + q*4];
            float4 QB = *(const float4*)&pq[rB*128 + 64 + q*4];
            float isdA = rsqrtf(fmaf(fmaf(qpoly[rA*4], wtA, qpoly[rA*4+1]), wtA, qpoly[rA*4+2]) + EPS);
            float isdB = rsqrtf(fmaf(fmaf(qpoly[rB*4], wtB, qpoly[rB*4+1]), wtB, qpoly[rB*4+2]) + EPS);
            float psA = 0.f, psB = 0.f;
            #pragma unroll
            for (int k = 0; k < 4; k++) {
                float rhA = fmaxf(fmaf(isdA, fmaf(((const float*)&PA)[k], wtA, ((const float*)&QA)[k]),
                                  ((const float*)&u4)[k] + ((const float*)&xaA)[k] + ((const float*)&xbA)[k]), 0.f);
                float rhB = fmaxf(fmaf(isdB, fmaf(((const float*)&PB)[k], wtB, ((const float*)&QB)[k]),
                                  ((const float*)&u4)[k] + ((const float*)&xaB)[k] + ((const float*)&xbB)[k]), 0.f);
                psA = fmaf(rhA, ((const float*)&w4)[k], psA);
                psB = fmaf(rhB, ((const float*)&w4)[k], psB);
            }
            #pragma unroll
            for (int m = 1; m <= 8; m <<= 1) {
                psA += __shfl_xor(psA, m, 64);
                psB += __shfl_xor(psB, m, 64);
            }
            if (q < 2) {
                bool isA = (q == 0);
                float ps    = isA ? psA : psB;
                float isd   = isA ? isdA : isdB;
                float wt_   = isA ? wtA : wtB;
                int   rr    = isA ? rA : rB;
                int   src_  = isA ? srcA : srcB;
                int   tgt_  = isA ? tgtA : tgtB;
                float score = 1.f / (1.f + __expf(-(ps + sb2)));
                float wf = 0.f, wr = 0.f;
                if (hier > 0.f) {
                    wf = hier * (1.f/(1.f + __expf(-tfj))) * 0.3f;
                    wr = hier * 0.1f;
                }
                if (sl < CAP) {
                    float4 rv;
                    rv.x = __builtin_bit_cast(float, (uint)(tgt_ | (rr << 12)));
                    rv.y = wf;
                    rv.z = score * isd * wt_;
                    rv.w = score * isd;
                    recS[src_*CAP + sl] = rv;
                }
                if (pt < CAP)
                    recT[tgt_*CAP + pt] = make_float2(__builtin_bit_cast(float, (uint)src_), wr);
            }
        }
    }
}

// ---------------- K3: attn_out + outp, 4 nodes/block, split-K x2 ----------------
__global__ __launch_bounds__(256) void k_out_base(
    const float* __restrict__ ctxT, const float* __restrict__ wt,
    const float* __restrict__ ab, const float* __restrict__ ob,
    float* __restrict__ base)
{
    __shared__ float cs[4][128];
    __shared__ float as[4][128];
    __shared__ float scr[2][4][128];
    int tid = threadIdx.x;
    int c = tid & 127, hf = tid >> 7;
    int n0 = blockIdx.x*4;
    if (hf == 0) {
        float4 cv = *(const float4*)(ctxT + c*4096 + n0);
        cs[0][c] = cv.x; cs[1][c] = cv.y; cs[2][c] = cv.z; cs[3][c] = cv.w;
    }
    __syncthreads();
    int i0 = hf*64;
    const float* awT = wt + T_AW;
    {
        float a0=0,a1=0,a2=0,a3=0;
        #pragma unroll 4
        for (int i = 0; i < 64; i++) {
            int ii = i0 + i;
            float w = awT[ii*128 + c];
            a0=fmaf(cs[0][ii],w,a0); a1=fmaf(cs[1][ii],w,a1);
            a2=fmaf(cs[2][ii],w,a2); a3=fmaf(cs[3][ii],w,a3);
        }
        scr[hf][0][c]=a0; scr[hf][1][c]=a1; scr[hf][2][c]=a2; scr[hf][3][c]=a3;
    }
    __syncthreads();
    if (hf == 0) {
        float abc = ab[c];
        #pragma unroll
        for (int j = 0; j < 4; j++) as[j][c] = scr[0][j][c] + scr[1][j][c] + abc;
    }
    __syncthreads();
    const float* owT = wt + T_OW;
    {
        float b0=0,b1=0,b2=0,b3=0;
        #pragma unroll 4
        for (int i = 0; i < 64; i++) {
            int ii = i0 + i;
            float w = owT[ii*128 + c];
            b0=fmaf(as[0][ii],w,b0); b1=fmaf(as[1][ii],w,b1);
            b2=fmaf(as[2][ii],w,b2); b3=fmaf(as[3][ii],w,b3);
        }
        scr[hf][0][c]=b0; scr[hf][1][c]=b1; scr[hf][2][c]=b2; scr[hf][3][c]=b3;
    }
    __syncthreads();
    if (hf == 0) {
        float obc = ob[c];
        #pragma unroll
        for (int j = 0; j < 4; j++)
            base[(n0+j)*128 + c] = scr[0][j][c] + scr[1][j][c] + obc;
    }
}

// ---------------- K7a: gather upd + nctx (score recomputed in-place) -> comb[n][192] ----------------
__global__ __launch_bounds__(256) void k_gather(
    const float* __restrict__ base, const float4* __restrict__ recS,
    const float2* __restrict__ recT, const int* __restrict__ cnt_s,
    const int* __restrict__ cnt_t,
    const float* __restrict__ tab, const float* __restrict__ ln_b,
    float* __restrict__ comb)
{
    __shared__ int   sIdx[CAP];
    __shared__ float sWf[CAP], sZ[CAP], sWc[CAP];
    __shared__ int   tIdx[CAP];
    __shared__ float tWr[CAP];
    __shared__ float zsum[33], wsum[33];
    __shared__ float ssum;
    __shared__ float partial[2][128];
    int n = blockIdx.x, tid = threadIdx.x;
    int ns = min(cnt_s[n], CAP);
    int nt = min(cnt_t[n], CAP);
    int nsp = (ns + 15) & ~15;
    int ntp = (nt + 15) & ~15;
    const float4* rs = recS + n*CAP;
    const float2* rt = recT + n*CAP;
    if (tid < 33) { zsum[tid] = 0.f; wsum[tid] = 0.f; }
    if (tid == 33) ssum = 0.f;
    for (int i = tid; i < nsp; i += 256) {
        if (i < ns) {
            float4 r = rs[i];
            sIdx[i] = (int)__builtin_bit_cast(uint, r.x);
            sWf[i] = r.y; sZ[i] = r.z; sWc[i] = r.w;
        } else { sIdx[i] = n; sWf[i] = 0.f; sZ[i] = 0.f; sWc[i] = 0.f; }
    }
    for (int i = tid; i < ntp; i += 256) {
        if (i < nt) {
            float2 r = rt[i];
            tIdx[i] = (int)__builtin_bit_cast(uint, r.x);
            tWr[i] = r.y;
        } else { tIdx[i] = n; tWr[i] = 0.f; }
    }
    __syncthreads();
    for (int i = tid; i < ns; i += 256) {
        int rg = (sIdx[i] >> 12) & 63;
        float zv = sZ[i], wv = sWc[i];
        atomicAdd(&zsum[rg], zv);
        atomicAdd(&wsum[rg], wv);
        float wt_ = zv / wv;
        float poly = fmaf(fmaf(tab[rg*320+256], wt_, tab[rg*320+257]), wt_, tab[rg*320+258]) + EPS;
        atomicAdd(&ssum, wv * sqrtf(poly));
    }
    {
        int c = tid & 127, half = tid >> 7;
        float a0=0.f,a1=0.f,a2=0.f,a3=0.f,a4=0.f,a5=0.f,a6=0.f,a7=0.f;
        for (int i = half*8; i < nsp; i += 16) {
            a0 = fmaf(base[(sIdx[i+0] & 4095)*128 + c], sWf[i+0], a0);
            a1 = fmaf(base[(sIdx[i+1] & 4095)*128 + c], sWf[i+1], a1);
            a2 = fmaf(base[(sIdx[i+2] & 4095)*128 + c], sWf[i+2], a2);
            a3 = fmaf(base[(sIdx[i+3] & 4095)*128 + c], sWf[i+3], a3);
            a4 = fmaf(base[(sIdx[i+4] & 4095)*128 + c], sWf[i+4], a4);
            a5 = fmaf(base[(sIdx[i+5] & 4095)*128 + c], sWf[i+5], a5);
            a6 = fmaf(base[(sIdx[i+6] & 4095)*128 + c], sWf[i+6], a6);
            a7 = fmaf(base[(sIdx[i+7] & 4095)*128 + c], sWf[i+7], a7);
        }
        for (int i = half*8; i < ntp; i += 16) {
            a0 = fmaf(base[tIdx[i+0]*128 + c], tWr[i+0], a0);
            a1 = fmaf(base[tIdx[i+1]*128 + c], tWr[i+1], a1);
            a2 = fmaf(base[tIdx[i+2]*128 + c], tWr[i+2], a2);
            a3 = fmaf(base[tIdx[i+3]*128 + c], tWr[i+3], a3);
            a4 = fmaf(base[tIdx[i+4]*128 + c], tWr[i+4], a4);
            a5 = fmaf(base[tIdx[i+5]*128 + c], tWr[i+5], a5);
            a6 = fmaf(base[tIdx[i+6]*128 + c], tWr[i+6], a6);
            a7 = fmaf(base[tIdx[i+7]*128 + c], tWr[i+7], a7);
        }
        partial[half][c] = ((a0+a1)+(a2+a3)) + ((a4+a5)+(a6+a7));
    }
    __syncthreads();
    if (tid < 128) {
        comb[n*192 + tid] = base[n*128 + tid] + partial[0][tid] + partial[1][tid];
    } else if (tid < 192) {
        int c3 = tid - 128;
        float acc = ssum*ln_b[c3];
        #pragma unroll
        for (int r = 0; r < 33; r++)
            acc += zsum[r]*tab[r*320 + c3] + wsum[r]*tab[r*320 + 64 + c3];
        comb[n*192 + tid] = acc;
    }
}

// ---------------- K7b: agg GEMM + LN + relu, 4 nodes/block ----------------
__global__ __launch_bounds__(256) void k_agg(
    const float* __restrict__ comb, const float* __restrict__ wt,
    const float* __restrict__ agg_b,
    const float* __restrict__ g, const float* __restrict__ b, float* __restrict__ out)
{
    __shared__ float cb[4][192];
    __shared__ float red[8];
    int n0 = blockIdx.x*4, tid = threadIdx.x;
    for (int i = tid; i < 768; i += 256) cb[i/192][i%192] = comb[n0*192 + i];
    __syncthreads();
    int c = tid;
    float ab = agg_b[c];
    float acc[4] = {ab, ab, ab, ab};
    const float* aggT = wt + T_AGG;
    #pragma unroll 4
    for (int i = 0; i < 192; i++) {
        float w = aggT[i*256 + c];
        acc[0]=fmaf(cb[0][i],w,acc[0]); acc[1]=fmaf(cb[1][i],w,acc[1]);
        acc[2]=fmaf(cb[2][i],w,acc[2]); acc[3]=fmaf(cb[3][i],w,acc[3]);
    }
    int lane = c & 63, w_ = c >> 6;
    float gc = g[c], bc = b[c];
    #pragma unroll
    for (int j = 0; j < 4; j++) {
        float a = acc[j];
        float s = a;
        #pragma unroll
        for (int m = 32; m >= 1; m >>= 1) s += __shfl_xor(s, m, 64);
        if (lane == 0) red[w_] = s;
        __syncthreads();
        float mu = (red[0]+red[1]+red[2]+red[3]) * (1.f/256.f);
        float d = a - mu;
        float s2 = d*d;
        #pragma unroll
        for (int m = 32; m >= 1; m >>= 1) s2 += __shfl_xor(s2, m, 64);
        if (lane == 0) red[4+w_] = s2;
        __syncthreads();
        float var = (red[4]+red[5]+red[6]+red[7]) * (1.f/256.f);
        float y = d * rsqrtf(var + EPS) * gc + bc;
        out[(n0+j)*256 + c] = fmaxf(y, 0.f);
        __syncthreads();
    }
}

extern "C" void kernel_launch(void* const* d_in, const int* in_sizes, int n_in,
                              void* d_out, int out_size, void* d_ws, size_t ws_size,
                              hipStream_t stream)
{
    const float* x        = (const float*)d_in[0];
    const int*   eidx     = (const int*)d_in[1];
    const float* etime    = (const float*)d_in[2];
    const float* eattr    = (const float*)d_in[3];
    const float* te_w1    = (const float*)d_in[4];
    const float* te_b1    = (const float*)d_in[5];
    const float* te_w2    = (const float*)d_in[6];
    const float* te_b2    = (const float*)d_in[7];
    const float* te_ln_g  = (const float*)d_in[8];
    const float* te_ln_b  = (const float*)d_in[9];
    const float* inp_w    = (const float*)d_in[10];
    const float* inp_b    = (const float*)d_in[11];
    const float* wq       = (const float*)d_in[12];
    const float* bq       = (const float*)d_in[13];
    const float* wk       = (const float*)d_in[14];
    const float* bk       = (const float*)d_in[15];
    const float* wv       = (const float*)d_in[16];
    const float* bv       = (const float*)d_in[17];
    const float* aow      = (const float*)d_in[18];
    const float* aob      = (const float*)d_in[19];
    const float* ow       = (const float*)d_in[20];
    const float* ob       = (const float*)d_in[21];
    const float* sc_w1    = (const float*)d_in[22];
    const float* sc_b1    = (const float*)d_in[23];
    const float* sc_w2    = (const float*)d_in[24];
    const float* sc_b2    = (const float*)d_in[25];
    const float* agg_w    = (const float*)d_in[26];
    const float* agg_b    = (const float*)d_in[27];
    const float* agg_g    = (const float*)d_in[28];
    const float* agg_bb   = (const float*)d_in[29];
    const float* decay    = (const float*)d_in[30];
    float* ws = (float*)d_ws;
    float* out = (float*)d_out;
    ushort* qb   = (ushort*)(ws + O_QB);
    ushort* kbuf = (ushort*)(ws + O_KB);
    ushort* vt   = (ushort*)(ws + O_VT);
    float4* recS = (float4*)(ws + O_RECS);
    float2* recT = (float2*)(ws + O_RECT);
    int* cnt_s   = (int*)(ws + O_CNTS);
    int* cnt_t   = (int*)(ws + O_CNTT);
    float* wtb   = ws + O_WT;
    float* comb  = ws + O_CMB;

    k_tr<<<640, 256, 0, stream>>>(inp_w, wq, wk, wv, aow, ow, sc_w1, agg_w, wtb,
                                  ws + O_CNTS);
    k_setup<<<33, 64, 0, stream>>>(te_w1, te_b1, te_w2, te_b2, te_ln_g, te_ln_b,
                                   sc_w1, ws+O_TAB, ws+O_AUX);
    k_proj_qkv<<<N_NODES/4, 256, 0, stream>>>(x, wtb, inp_b, bq, bk, bv, qb, kbuf, vt,
                                              ws+O_XSA, ws+O_XTB);
    k_ea<<<4608, 512, 0, stream>>>(qb, kbuf, vt, ws+O_CTXT,
                                   eidx, etime, eattr, ws+O_TAB, ws+O_AUX,
                                   sc_b1, sc_w2, sc_b2, decay,
                                   ws+O_XSA, ws+O_XTB,
                                   cnt_s, cnt_t, recS, recT);
    k_out_base<<<N_NODES/4, 256, 0, stream>>>(ws+O_CTXT, wtb, aob, ob, ws+O_BASE);
    k_gather<<<N_NODES, 256, 0, stream>>>(ws+O_BASE, recS, recT, cnt_s, cnt_t,
                                          ws+O_TAB, te_ln_b, comb);
    k_agg<<<N_NODES/4, 256, 0, stream>>>(comb, wtb, agg_b, agg_g, agg_bb, out);
}

// Round 23
// 156.631 us; speedup vs baseline: 1.1200x; 1.1200x over previous
//
#include <hip/hip_runtime.h>

#define N_NODES 4096
#define N_EDGES 262144
#define EPS 1e-5f
#define CAP 192

// workspace offsets (float units)
#define O_CTXT 0        // ctx^T f32 [128][4096]
#define O_BASE 524288   // base [4096][128]
#define O_XSA  1048576
#define O_XTB  1310720
#define O_TAB  1572864  // 33 regions x 320
#define O_AUX  1583424  // thr[32] + R0[64]
#define O_RECS 1583552  // float4 [4096][CAP]
#define O_RECT 4729280  // float2 [4096][CAP]
#define O_CNTS 6826432
#define O_CNTT 6830528
#define O_QB   6838720  // bf16 [4][4096][32]
#define O_KB   7100864
#define O_VT   7363008  // bf16 [4][32][4096]
#define O_WT   7625152  // transposed weights
#define O_CMB  7788992  // comb [4096][192]
// within WT:
#define T_INP  0
#define T_WQ   16384
#define T_WK   32768
#define T_WV   49152
#define T_AW   65536
#define T_OW   81920
#define T_SC   98304
#define T_AGG  114688   // [192][256]

typedef __attribute__((ext_vector_type(8))) short short8v;
typedef __attribute__((ext_vector_type(4))) float f32x4;

__device__ __forceinline__ ushort f2bf(float x) {
    uint u = __builtin_bit_cast(uint, x);
    uint r = (u + 0x7FFFu + ((u >> 16) & 1u)) >> 16;
    return (ushort)r;
}
__device__ __forceinline__ float fexp2(float x) { return __builtin_amdgcn_exp2f(x); }

// ---------------- K-1: one-time weight transposes + counter zeroing ----------------
__global__ __launch_bounds__(256) void k_tr(
    const float* __restrict__ inp_w, const float* __restrict__ wq,
    const float* __restrict__ wk, const float* __restrict__ wv,
    const float* __restrict__ aw, const float* __restrict__ ow,
    const float* __restrict__ sc_w1, const float* __restrict__ agg_w,
    float* __restrict__ wt, float* __restrict__ zbuf)
{
    int idx = blockIdx.x*256 + threadIdx.x;
    if (idx < 8192) zbuf[idx] = 0.f;   // cnt_s, cnt_t (contiguous)
    if (idx < 114688) {
        int m = idx >> 14;
        int r = idx & 16383;
        int i = r >> 7, c = r & 127;
        float v;
        switch (m) {
            case 0: v = inp_w[c*128+i]; break;
            case 1: v = wq[c*128+i]; break;
            case 2: v = wk[c*128+i]; break;
            case 3: v = wv[c*128+i]; break;
            case 4: v = aw[c*128+i]; break;
            case 5: v = ow[c*128+i]; break;
            default: v = (c < 64) ? sc_w1[c*320+i] : sc_w1[(c-64)*320+128+i]; break;
        }
        wt[idx] = v;
    } else {
        int a = idx - 114688;
        int i = a >> 8, c = a & 255;
        wt[idx] = agg_w[c*192 + i];
    }
}

// ---------------- K0: region tables for piecewise-linear temporal MLP ----------------
__global__ __launch_bounds__(64) void k_setup(
    const float* __restrict__ te_w1, const float* __restrict__ te_b1,
    const float* __restrict__ te_w2, const float* __restrict__ te_b2,
    const float* __restrict__ ln_g, const float* __restrict__ ln_b,
    const float* __restrict__ sc_w1, float* __restrict__ tab, float* __restrict__ aux)
{
    __shared__ float t_s[32];
    __shared__ int pos_s[32];
    __shared__ float AG_s[64], BG_s[64];
    int r = blockIdx.x;
    int c = threadIdx.x;
    if (c < 32) {
        float w = te_w1[c], b = te_b1[c];
        t_s[c] = (w != 0.f) ? (-b / w) : 1e30f;
    }
    __syncthreads();
    if (c < 32) {
        float t = t_s[c];
        int p = 0;
        for (int i = 0; i < 32; i++) {
            float ti = t_s[i];
            p += (ti < t) || (ti == t && i < c);
        }
        pos_s[c] = p;
    }
    __syncthreads();
    float A = 0.f, B = te_b2[c];
    for (int j = 0; j < 32; j++) {
        float w = te_w1[j], b = te_b1[j];
        bool act = (w > 0.f) ? (pos_s[j] < r) : ((w < 0.f) ? (pos_s[j] >= r) : (b > 0.f));
        if (act) { float w2 = te_w2[c*32 + j]; A += w * w2; B += b * w2; }
    }
    float mA = A, mB = B;
    #pragma unroll
    for (int m = 32; m >= 1; m >>= 1) { mA += __shfl_xor(mA, m, 64); mB += __shfl_xor(mB, m, 64); }
    mA *= (1.f/64.f); mB *= (1.f/64.f);
    float a = A - mA, bq = B - mB;
    float qa = a*a, qb = a*bq, qc = bq*bq;
    #pragma unroll
    for (int m = 32; m >= 1; m >>= 1) {
        qa += __shfl_xor(qa, m, 64); qb += __shfl_xor(qb, m, 64); qc += __shfl_xor(qc, m, 64);
    }
    qa *= (1.f/64.f); qb *= (2.f/64.f); qc *= (1.f/64.f);
    float g = ln_g[c];
    float AG = a*g, BG = bq*g;
    AG_s[c] = AG; BG_s[c] = BG;
    float* row = tab + r*320;
    row[c] = AG; row[64+c] = BG;
    if (c == 0) { row[256] = qa; row[257] = qb; row[258] = qc; }
    __syncthreads();
    const float* wc = sc_w1 + c*320 + 256;
    float P = 0.f, Q = 0.f;
    for (int j = 0; j < 64; j++) { float w = wc[j]; P += AG_s[j]*w; Q += BG_s[j]*w; }
    row[128+c] = P; row[192+c] = Q;
    if (r == 0) {
        if (c < 32) aux[pos_s[c]] = t_s[c];
        float R0 = 0.f;
        for (int j = 0; j < 64; j++) R0 += ln_b[j] * wc[j];
        aux[32 + c] = R0;
    }
}

// ---------------- K1: projections + sc partials, 4 nodes/block, split-K x2 ----------------
__global__ __launch_bounds__(256) void k_proj_qkv(
    const float* __restrict__ x, const float* __restrict__ wt,
    const float* __restrict__ inp_b,
    const float* __restrict__ bq, const float* __restrict__ bk, const float* __restrict__ bv,
    ushort* __restrict__ qb, ushort* __restrict__ kbuf, ushort* __restrict__ vt,
    float* __restrict__ xsa, float* __restrict__ xtb)
{
    __shared__ float xs[512];
    __shared__ float xps[4][128];
    __shared__ float scrA[2][4][128];
    __shared__ float scrB[2][4][128];
    __shared__ float scrC[2][4][128];
    int tid = threadIdx.x;
    int c = tid & 127, hf = tid >> 7;
    int n0 = blockIdx.x*4;
    for (int i = tid; i < 512; i += 256) xs[i] = x[n0*128 + i];
    __syncthreads();
    int i0 = hf*64;
    const float* inpT = wt + T_INP;
    const float* scT  = wt + T_SC;
    {
        float a0=0,a1=0,a2=0,a3=0, s0=0,s1=0,s2=0,s3=0;
        #pragma unroll 4
        for (int i = 0; i < 64; i++) {
            int ii = i0 + i;
            float w  = inpT[ii*128 + c];
            float ws = scT[ii*128 + c];
            float x0 = xs[ii], x1 = xs[128+ii], x2 = xs[256+ii], x3 = xs[384+ii];
            a0=fmaf(x0,w,a0); a1=fmaf(x1,w,a1); a2=fmaf(x2,w,a2); a3=fmaf(x3,w,a3);
            s0=fmaf(x0,ws,s0); s1=fmaf(x1,ws,s1); s2=fmaf(x2,ws,s2); s3=fmaf(x3,ws,s3);
        }
        scrA[hf][0][c]=a0; scrA[hf][1][c]=a1; scrA[hf][2][c]=a2; scrA[hf][3][c]=a3;
        scrB[hf][0][c]=s0; scrB[hf][1][c]=s1; scrB[hf][2][c]=s2; scrB[hf][3][c]=s3;
    }
    __syncthreads();
    if (hf == 0) {
        float ib = inp_b[c];
        #pragma unroll
        for (int j = 0; j < 4; j++) xps[j][c] = scrA[0][j][c] + scrA[1][j][c] + ib;
    } else {
        #pragma unroll
        for (int j = 0; j < 4; j++) {
            float sv = scrB[0][j][c] + scrB[1][j][c];
            int n = n0 + j;
            if (c < 64) xsa[n*64+c] = sv; else xtb[n*64+(c-64)] = sv;
        }
    }
    __syncthreads();
    const float* wqT = wt + T_WQ;
    const float* wkT = wt + T_WK;
    const float* wvT = wt + T_WV;
    {
        float q0=0,q1=0,q2=0,q3=0,k0=0,k1=0,k2=0,k3=0,v0=0,v1=0,v2=0,v3=0;
        #pragma unroll 2
        for (int i = 0; i < 64; i++) {
            int ii = i0 + i;
            float wQ = wqT[ii*128 + c], wK = wkT[ii*128 + c], wV = wvT[ii*128 + c];
            float x0 = xps[0][ii], x1 = xps[1][ii], x2 = xps[2][ii], x3 = xps[3][ii];
            q0=fmaf(x0,wQ,q0); q1=fmaf(x1,wQ,q1); q2=fmaf(x2,wQ,q2); q3=fmaf(x3,wQ,q3);
            k0=fmaf(x0,wK,k0); k1=fmaf(x1,wK,k1); k2=fmaf(x2,wK,k2); k3=fmaf(x3,wK,k3);
            v0=fmaf(x0,wV,v0); v1=fmaf(x1,wV,v1); v2=fmaf(x2,wV,v2); v3=fmaf(x3,wV,v3);
        }
        scrA[hf][0][c]=q0; scrA[hf][1][c]=q1; scrA[hf][2][c]=q2; scrA[hf][3][c]=q3;
        scrB[hf][0][c]=k0; scrB[hf][1][c]=k1; scrB[hf][2][c]=k2; scrB[hf][3][c]=k3;
        scrC[hf][0][c]=v0; scrC[hf][1][c]=v1; scrC[hf][2][c]=v2; scrC[hf][3][c]=v3;
    }
    __syncthreads();
    const float QSCALE = 0.17677669529663687f * 1.4426950408889634f;
    int h = c >> 5, d = c & 31;
    if (hf == 0) {
        float bqc = bq[c], bkc = bk[c];
        #pragma unroll
        for (int j = 0; j < 4; j++) {
            int n = n0 + j;
            int qi = h*131072 + n*32 + d;
            float qv = scrA[0][j][c] + scrA[1][j][c] + bqc;
            float kv = scrB[0][j][c] + scrB[1][j][c] + bkc;
            qb[qi]   = f2bf(qv * QSCALE);
            kbuf[qi] = f2bf(kv);
        }
    } else {
        float bvc = bv[c];
        #pragma unroll
        for (int j = 0; j < 4; j++) {
            int n = n0 + j;
            float vv = scrC[0][j][c] + scrC[1][j][c] + bvc;
            vt[c*4096 + n] = f2bf(vv);
        }
    }
}

// ---------------- K2+K6 FUSED: dual-role kernel (attn blocks + edge blocks) ----------------
// grid 1536 x 512. blockIdx%3==1 -> attention (bxa = blockIdx/3, 512 blocks);
// else -> edge (bxe in [0,1024), 8 waves x 8 edges x 4 iters = 256 edges/block).
// Roles interleave in dispatch order so each CU hosts both: edge-atomic stalls
// are filled by attn MFMA work. Shared 18432B arena aliased per role.
__global__ __launch_bounds__(512) void k_ea(
    const ushort* __restrict__ qb, const ushort* __restrict__ kb,
    const ushort* __restrict__ vt, float* __restrict__ ctxT,
    const int* __restrict__ eidx, const float* __restrict__ etime,
    const float* __restrict__ eattr,
    const float* __restrict__ tab, const float* __restrict__ aux,
    const float* __restrict__ sc_b1, const float* __restrict__ sc_w2,
    const float* __restrict__ sc_b2, const float* __restrict__ decay_p,
    const float* __restrict__ xsa, const float* __restrict__ xtb,
    int* __restrict__ cnt_s, int* __restrict__ cnt_t,
    float4* __restrict__ recS, float2* __restrict__ recT)
{
    __shared__ float smem[4608];   // 18432 B arena
    int tid = threadIdx.x;
    int lane = tid & 63;
    int wv = tid >> 6;
    int bm = blockIdx.x % 3;
    if (bm == 1) {
        // ================= ATTENTION ROLE =================
        float* lw0  = smem;            // [8][16]
        float* lw1  = smem + 128;      // [8][16]
        float* obuf = smem + 256;      // [8][512]
        int bxa = blockIdx.x / 3;
        int h = bxa & 3;
        int qg = bxa >> 2;
        int q15 = lane & 15;
        int g = lane >> 4;
        const ushort* qhb = qb + h*131072;
        const ushort* khb = kb + h*131072;
        const ushort* vhb = vt + h*131072;
        short8v qf0 = *(const short8v*)(qhb + (qg*32 + q15)*32 + g*8);
        short8v qf1 = *(const short8v*)(qhb + (qg*32 + 16 + q15)*32 + g*8);
        int key0off = ((q15 >> 2) << 3) + (q15 & 3);
        const f32x4 z = {0.f,0.f,0.f,0.f};
        f32x4 o0a = z, o1a = z, o0b = z, o1b = z;
        float lsum0 = 0.f, lsum1 = 0.f;
        int kstart = wv * 512;
        #pragma unroll 2
        for (int k32 = kstart; k32 < kstart + 512; k32 += 32) {
            short8v kf0 = *(const short8v*)(khb + (k32 + key0off)*32 + g*8);
            short8v kf1 = *(const short8v*)(khb + (k32 + key0off + 4)*32 + g*8);
            short8v vf0 = *(const short8v*)(vhb + q15*4096 + k32 + g*8);
            short8v vf1 = *(const short8v*)(vhb + (16 + q15)*4096 + k32 + g*8);
            f32x4 s0a = __builtin_amdgcn_mfma_f32_16x16x32_bf16(kf0, qf0, z, 0, 0, 0);
            f32x4 s1a = __builtin_amdgcn_mfma_f32_16x16x32_bf16(kf1, qf0, z, 0, 0, 0);
            f32x4 s0b = __builtin_amdgcn_mfma_f32_16x16x32_bf16(kf0, qf1, z, 0, 0, 0);
            f32x4 s1b = __builtin_amdgcn_mfma_f32_16x16x32_bf16(kf1, qf1, z, 0, 0, 0);
            float p0 = fexp2(s0a[0]), p1 = fexp2(s0a[1]);
            float p2 = fexp2(s0a[2]), p3 = fexp2(s0a[3]);
            float p4 = fexp2(s1a[0]), p5 = fexp2(s1a[1]);
            float p6 = fexp2(s1a[2]), p7 = fexp2(s1a[3]);
            lsum0 += ((p0 + p1) + (p2 + p3)) + ((p4 + p5) + (p6 + p7));
            short8v pfa;
            pfa[0] = (short)f2bf(p0); pfa[1] = (short)f2bf(p1);
            pfa[2] = (short)f2bf(p2); pfa[3] = (short)f2bf(p3);
            pfa[4] = (short)f2bf(p4); pfa[5] = (short)f2bf(p5);
            pfa[6] = (short)f2bf(p6); pfa[7] = (short)f2bf(p7);
            float r0 = fexp2(s0b[0]), r1 = fexp2(s0b[1]);
            float r2 = fexp2(s0b[2]), r3 = fexp2(s0b[3]);
            float r4 = fexp2(s1b[0]), r5 = fexp2(s1b[1]);
            float r6 = fexp2(s1b[2]), r7 = fexp2(s1b[3]);
            lsum1 += ((r0 + r1) + (r2 + r3)) + ((r4 + r5) + (r6 + r7));
            short8v pfb;
            pfb[0] = (short)f2bf(r0); pfb[1] = (short)f2bf(r1);
            pfb[2] = (short)f2bf(r2); pfb[3] = (short)f2bf(r3);
            pfb[4] = (short)f2bf(r4); pfb[5] = (short)f2bf(r5);
            pfb[6] = (short)f2bf(r6); pfb[7] = (short)f2bf(r7);
            o0a = __builtin_amdgcn_mfma_f32_16x16x32_bf16(vf0, pfa, o0a, 0, 0, 0);
            o1a = __builtin_amdgcn_mfma_f32_16x16x32_bf16(vf1, pfa, o1a, 0, 0, 0);
            o0b = __builtin_amdgcn_mfma_f32_16x16x32_bf16(vf0, pfb, o0b, 0, 0, 0);
            o1b = __builtin_amdgcn_mfma_f32_16x16x32_bf16(vf1, pfb, o1b, 0, 0, 0);
        }
        lsum0 += __shfl_xor(lsum0, 16, 64);
        lsum0 += __shfl_xor(lsum0, 32, 64);
        lsum1 += __shfl_xor(lsum1, 16, 64);
        lsum1 += __shfl_xor(lsum1, 32, 64);
        if (lane < 16) { lw0[wv*16 + lane] = lsum0; lw1[wv*16 + lane] = lsum1; }
        #pragma unroll
        for (int r = 0; r < 4; r++) {
            obuf[wv*512 + r*64 + lane]       = o0a[r];
            obuf[wv*512 + (4 + r)*64 + lane] = o1a[r];
        }
        __syncthreads();
        {
            int e = tid;
            int lp = e & 63, r8 = e >> 6;
            int q = lp & 15;
            float L = ((lw0[0*16+q]+lw0[1*16+q]) + (lw0[2*16+q]+lw0[3*16+q]))
                    + ((lw0[4*16+q]+lw0[5*16+q]) + (lw0[6*16+q]+lw0[7*16+q]));
            float a = ((obuf[0*512+e]+obuf[1*512+e]) + (obuf[2*512+e]+obuf[3*512+e]))
                    + ((obuf[4*512+e]+obuf[5*512+e]) + (obuf[6*512+e]+obuf[7*512+e]));
            int d = ((lp >> 4) << 2) + (r8 & 3) + ((r8 >> 2) << 4);
            ctxT[(h*32 + d)*4096 + qg*32 + q] = a / L;
        }
        __syncthreads();
        #pragma unroll
        for (int r = 0; r < 4; r++) {
            obuf[wv*512 + r*64 + lane]       = o0b[r];
            obuf[wv*512 + (4 + r)*64 + lane] = o1b[r];
        }
        __syncthreads();
        {
            int e = tid;
            int lp = e & 63, r8 = e >> 6;
            int q = lp & 15;
            float L = ((lw1[0*16+q]+lw1[1*16+q]) + (lw1[2*16+q]+lw1[3*16+q]))
                    + ((lw1[4*16+q]+lw1[5*16+q]) + (lw1[6*16+q]+lw1[7*16+q]));
            float a = ((obuf[0*512+e]+obuf[1*512+e]) + (obuf[2*512+e]+obuf[3*512+e]))
                    + ((obuf[4*512+e]+obuf[5*512+e]) + (obuf[6*512+e]+obuf[7*512+e]));
            int d = ((lp >> 4) << 2) + (r8 & 3) + ((r8 >> 2) << 4);
            ctxT[(h*32 + d)*4096 + qg*32 + 16 + q] = a / L;
        }
    } else {
        // ================= EDGE ROLE (round-16 structure, 8 waves) =================
        float* pq    = smem;            // [33*128]
        float* qpoly = smem + 4224;     // [33*4]
        float* thrL  = smem + 4356;     // [32]
        float* u0L   = smem + 4388;     // [64]
        float* sw2L  = smem + 4452;     // [64]
        int bxe = (blockIdx.x / 3) * 2 + ((bm == 2) ? 1 : 0);
        for (int i = tid; i < 33*128; i += 512)
            pq[i] = tab[(i >> 7)*320 + 128 + (i & 127)];
        if (tid < 33) {
            qpoly[tid*4+0] = tab[tid*320+256];
            qpoly[tid*4+1] = tab[tid*320+257];
            qpoly[tid*4+2] = tab[tid*320+258];
        }
        if (tid < 32) thrL[tid] = aux[tid];
        if (tid < 64) { u0L[tid] = sc_b1[tid] + aux[32+tid]; sw2L[tid] = sc_w2[tid]; }
        __syncthreads();
        float decay = decay_p[0];
        float sb2 = sc_b2[0];
        int g = lane >> 4, q = lane & 15;
        float th1 = thrL[q], th2 = thrL[16 + q];
        float4 u4 = *(const float4*)&u0L[q*4];
        float4 w4 = *(const float4*)&sw2L[q*4];
        for (int it = 0; it < 4; it++) {
            int base_e = bxe*256 + it*64;
            int eA = base_e + wv*8 + g;
            int eB = eA + 4;
            int srcA = eidx[eA], tgtA = eidx[N_EDGES + eA];
            int srcB = eidx[eB], tgtB = eidx[N_EDGES + eB];
            float tA = etime[eA], tB = etime[eB];
            float hier = 0.f, tfj = 0.f;
            int sl = 0, pt = 0;
            if (q == 0) {
                sl = atomicAdd(&cnt_s[srcA], 1);
                pt = atomicAdd(&cnt_t[tgtA], 1);
                hier = eattr[eA*17 + 16]; tfj = eattr[eA*17 + 5];
            } else if (q == 1) {
                sl = atomicAdd(&cnt_s[srcB], 1);
                pt = atomicAdd(&cnt_t[tgtB], 1);
                hier = eattr[eB*17 + 16]; tfj = eattr[eB*17 + 5];
            }
            float wtA = tA * __expf(-fabsf(tA)*decay);
            float wtB = tB * __expf(-fabsf(tB)*decay);
            unsigned long long bA1 = __ballot(wtA > th1);
            unsigned long long bA2 = __ballot(wtA > th2);
            unsigned long long bB1 = __ballot(wtB > th1);
            unsigned long long bB2 = __ballot(wtB > th2);
            int sh = g*16;
            int rA = __popc((uint)((bA1 >> sh) & 0xFFFF)) + __popc((uint)((bA2 >> sh) & 0xFFFF));
            int rB = __popc((uint)((bB1 >> sh) & 0xFFFF)) + __popc((uint)((bB2 >> sh) & 0xFFFF));
            float4 xaA = *(const float4*)&xsa[srcA*64 + q*4];
            float4 xbA = *(const float4*)&xtb[tgtA*64 + q*4];
            float4 xaB = *(const float4*)&xsa[srcB*64 + q*4];
            float4 xbB = *(const float4*)&xtb[tgtB*64 + q*4];
            float4 PA = *(const float4*)&pq[rA*128 + q*4];
            float4 QA = *(const float4*)&pq[rA*128 + 64 + q*4];
            float4 PB = *(const float4*)&pq[rB*128 + q*4];
            float4 QB = *(const float4*)&pq[rB*128 + 64 + q*4];
            float isdA = rsqrtf(fmaf(fmaf(qpoly[rA*4], wtA, qpoly[rA*4+1]), wtA, qpoly[rA*4+2]) + EPS);
            float isdB = rsqrtf(fmaf(fmaf(qpoly[rB*4], wtB, qpoly[rB*4+1]), wtB, qpoly[rB*4+2]) + EPS);
            float psA = 0.f, psB = 0.f;
            #pragma unroll
            for (int k = 0; k < 4; k++) {
                float rhA = fmaxf(fmaf(isdA, fmaf(((const float*)&PA)[k], wtA, ((const float*)&QA)[k]),
                                  ((const float*)&u4)[k] + ((const float*)&xaA)[k] + ((const float*)&xbA)[k]), 0.f);
                float rhB = fmaxf(fmaf(isdB, fmaf(((const float*)&PB)[k], wtB, ((const float*)&QB)[k]),
                                  ((const float*)&u4)[k] + ((const float*)&xaB)[k] + ((const float*)&xbB)[k]), 0.f);
                psA = fmaf(rhA, ((const float*)&w4)[k], psA);
                psB = fmaf(rhB, ((const float*)&w4)[k], psB);
            }
            #pragma unroll
            for (int m = 1; m <= 8; m <<= 1) {
                psA += __shfl_xor(psA, m, 64);
                psB += __shfl_xor(psB, m, 64);
            }
            if (q < 2) {
                bool isA = (q == 0);
                float ps    = isA ? psA : psB;
                float isd   = isA ? isdA : isdB;
                float wt_   = isA ? wtA : wtB;
                int   rr    = isA ? rA : rB;
                int   src_  = isA ? srcA : srcB;
                int   tgt_  = isA ? tgtA : tgtB;
                float score = 1.f / (1.f + __expf(-(ps + sb2)));
                float wf = 0.f, wr = 0.f;
                if (hier > 0.f) {
                    wf = hier * (1.f/(1.f + __expf(-tfj))) * 0.3f;
                    wr = hier * 0.1f;
                }
                if (sl < CAP) {
                    float4 rv;
                    rv.x = __builtin_bit_cast(float, (uint)(tgt_ | (rr << 12)));
                    rv.y = wf;
                    rv.z = score * isd * wt_;
                    rv.w = score * isd;
                    recS[src_*CAP + sl] = rv;
                }
                if (pt < CAP)
                    recT[tgt_*CAP + pt] = make_float2(__builtin_bit_cast(float, (uint)src_), wr);
            }
        }
    }
}

// ---------------- K3: attn_out + outp, 4 nodes/block, split-K x2 ----------------
__global__ __launch_bounds__(256) void k_out_base(
    const float* __restrict__ ctxT, const float* __restrict__ wt,
    const float* __restrict__ ab, const float* __restrict__ ob,
    float* __restrict__ base)
{
    __shared__ float cs[4][128];
    __shared__ float as[4][128];
    __shared__ float scr[2][4][128];
    int tid = threadIdx.x;
    int c = tid & 127, hf = tid >> 7;
    int n0 = blockIdx.x*4;
    if (hf == 0) {
        float4 cv = *(const float4*)(ctxT + c*4096 + n0);
        cs[0][c] = cv.x; cs[1][c] = cv.y; cs[2][c] = cv.z; cs[3][c] = cv.w;
    }
    __syncthreads();
    int i0 = hf*64;
    const float* awT = wt + T_AW;
    {
        float a0=0,a1=0,a2=0,a3=0;
        #pragma unroll 4
        for (int i = 0; i < 64; i++) {
            int ii = i0 + i;
            float w = awT[ii*128 + c];
            a0=fmaf(cs[0][ii],w,a0); a1=fmaf(cs[1][ii],w,a1);
            a2=fmaf(cs[2][ii],w,a2); a3=fmaf(cs[3][ii],w,a3);
        }
        scr[hf][0][c]=a0; scr[hf][1][c]=a1; scr[hf][2][c]=a2; scr[hf][3][c]=a3;
    }
    __syncthreads();
    if (hf == 0) {
        float abc = ab[c];
        #pragma unroll
        for (int j = 0; j < 4; j++) as[j][c] = scr[0][j][c] + scr[1][j][c] + abc;
    }
    __syncthreads();
    const float* owT = wt + T_OW;
    {
        float b0=0,b1=0,b2=0,b3=0;
        #pragma unroll 4
        for (int i = 0; i < 64; i++) {
            int ii = i0 + i;
            float w = owT[ii*128 + c];
            b0=fmaf(as[0][ii],w,b0); b1=fmaf(as[1][ii],w,b1);
            b2=fmaf(as[2][ii],w,b2); b3=fmaf(as[3][ii],w,b3);
        }
        scr[hf][0][c]=b0; scr[hf][1][c]=b1; scr[hf][2][c]=b2; scr[hf][3][c]=b3;
    }
    __syncthreads();
    if (hf == 0) {
        float obc = ob[c];
        #pragma unroll
        for (int j = 0; j < 4; j++)
            base[(n0+j)*128 + c] = scr[0][j][c] + scr[1][j][c] + obc;
    }
}

// ---------------- K7a: gather upd + nctx (score recomputed in-place) -> comb[n][192] ----------------
__global__ __launch_bounds__(256) void k_gather(
    const float* __restrict__ base, const float4* __restrict__ recS,
    const float2* __restrict__ recT, const int* __restrict__ cnt_s,
    const int* __restrict__ cnt_t,
    const float* __restrict__ tab, const float* __restrict__ ln_b,
    float* __restrict__ comb)
{
    __shared__ int   sIdx[CAP];
    __shared__ float sWf[CAP], sZ[CAP], sWc[CAP];
    __shared__ int   tIdx[CAP];
    __shared__ float tWr[CAP];
    __shared__ float zsum[33], wsum[33];
    __shared__ float ssum;
    __shared__ float partial[2][128];
    int n = blockIdx.x, tid = threadIdx.x;
    int ns = min(cnt_s[n], CAP);
    int nt = min(cnt_t[n], CAP);
    int nsp = (ns + 15) & ~15;
    int ntp = (nt + 15) & ~15;
    const float4* rs = recS + n*CAP;
    const float2* rt = recT + n*CAP;
    if (tid < 33) { zsum[tid] = 0.f; wsum[tid] = 0.f; }
    if (tid == 33) ssum = 0.f;
    for (int i = tid; i < nsp; i += 256) {
        if (i < ns) {
            float4 r = rs[i];
            sIdx[i] = (int)__builtin_bit_cast(uint, r.x);
            sWf[i] = r.y; sZ[i] = r.z; sWc[i] = r.w;
        } else { sIdx[i] = n; sWf[i] = 0.f; sZ[i] = 0.f; sWc[i] = 0.f; }
    }
    for (int i = tid; i < ntp; i += 256) {
        if (i < nt) {
            float2 r = rt[i];
            tIdx[i] = (int)__builtin_bit_cast(uint, r.x);
            tWr[i] = r.y;
        } else { tIdx[i] = n; tWr[i] = 0.f; }
    }
    __syncthreads();
    for (int i = tid; i < ns; i += 256) {
        int rg = (sIdx[i] >> 12) & 63;
        float zv = sZ[i], wv = sWc[i];
        atomicAdd(&zsum[rg], zv);
        atomicAdd(&wsum[rg], wv);
        float wt_ = zv / wv;
        float poly = fmaf(fmaf(tab[rg*320+256], wt_, tab[rg*320+257]), wt_, tab[rg*320+258]) + EPS;
        atomicAdd(&ssum, wv * sqrtf(poly));
    }
    {
        int c = tid & 127, half = tid >> 7;
        float a0=0.f,a1=0.f,a2=0.f,a3=0.f,a4=0.f,a5=0.f,a6=0.f,a7=0.f;
        for (int i = half*8; i < nsp; i += 16) {
            a0 = fmaf(base[(sIdx[i+0] & 4095)*128 + c], sWf[i+0], a0);
            a1 = fmaf(base[(sIdx[i+1] & 4095)*128 + c], sWf[i+1], a1);
            a2 = fmaf(base[(sIdx[i+2] & 4095)*128 + c], sWf[i+2], a2);
            a3 = fmaf(base[(sIdx[i+3] & 4095)*128 + c], sWf[i+3], a3);
            a4 = fmaf(base[(sIdx[i+4] & 4095)*128 + c], sWf[i+4], a4);
            a5 = fmaf(base[(sIdx[i+5] & 4095)*128 + c], sWf[i+5], a5);
            a6 = fmaf(base[(sIdx[i+6] & 4095)*128 + c], sWf[i+6], a6);
            a7 = fmaf(base[(sIdx[i+7] & 4095)*128 + c], sWf[i+7], a7);
        }
        for (int i = half*8; i < ntp; i += 16) {
            a0 = fmaf(base[tIdx[i+0]*128 + c], tWr[i+0], a0);
            a1 = fmaf(base[tIdx[i+1]*128 + c], tWr[i+1], a1);
            a2 = fmaf(base[tIdx[i+2]*128 + c], tWr[i+2], a2);
            a3 = fmaf(base[tIdx[i+3]*128 + c], tWr[i+3], a3);
            a4 = fmaf(base[tIdx[i+4]*128 + c], tWr[i+4], a4);
            a5 = fmaf(base[tIdx[i+5]*128 + c], tWr[i+5], a5);
            a6 = fmaf(base[tIdx[i+6]*128 + c], tWr[i+6], a6);
            a7 = fmaf(base[tIdx[i+7]*128 + c], tWr[i+7], a7);
        }
        partial[half][c] = ((a0+a1)+(a2+a3)) + ((a4+a5)+(a6+a7));
    }
    __syncthreads();
    if (tid < 128) {
        comb[n*192 + tid] = base[n*128 + tid] + partial[0][tid] + partial[1][tid];
    } else if (tid < 192) {
        int c3 = tid - 128;
        float acc = ssum*ln_b[c3];
        #pragma unroll
        for (int r = 0; r < 33; r++)
            acc += zsum[r]*tab[r*320 + c3] + wsum[r]*tab[r*320 + 64 + c3];
        comb[n*192 + tid] = acc;
    }
}

// ---------------- K7b: agg GEMM + LN + relu, 4 nodes/block ----------------
__global__ __launch_bounds__(256) void k_agg(
    const float* __restrict__ comb, const float* __restrict__ wt,
    const float* __restrict__ agg_b,
    const float* __restrict__ g, const float* __restrict__ b, float* __restrict__ out)
{
    __shared__ float cb[4][192];
    __shared__ float red[8];
    int n0 = blockIdx.x*4, tid = threadIdx.x;
    for (int i = tid; i < 768; i += 256) cb[i/192][i%192] = comb[n0*192 + i];
    __syncthreads();
    int c = tid;
    float ab = agg_b[c];
    float acc[4] = {ab, ab, ab, ab};
    const float* aggT = wt + T_AGG;
    #pragma unroll 4
    for (int i = 0; i < 192; i++) {
        float w = aggT[i*256 + c];
        acc[0]=fmaf(cb[0][i],w,acc[0]); acc[1]=fmaf(cb[1][i],w,acc[1]);
        acc[2]=fmaf(cb[2][i],w,acc[2]); acc[3]=fmaf(cb[3][i],w,acc[3]);
    }
    int lane = c & 63, w_ = c >> 6;
    float gc = g[c], bc = b[c];
    #pragma unroll
    for (int j = 0; j < 4; j++) {
        float a = acc[j];
        float s = a;
        #pragma unroll
        for (int m = 32; m >= 1; m >>= 1) s += __shfl_xor(s, m, 64);
        if (lane == 0) red[w_] = s;
        __syncthreads();
        float mu = (red[0]+red[1]+red[2]+red[3]) * (1.f/256.f);
        float d = a - mu;
        float s2 = d*d;
        #pragma unroll
        for (int m = 32; m >= 1; m >>= 1) s2 += __shfl_xor(s2, m, 64);
        if (lane == 0) red[4+w_] = s2;
        __syncthreads();
        float var = (red[4]+red[5]+red[6]+red[7]) * (1.f/256.f);
        float y = d * rsqrtf(var + EPS) * gc + bc;
        out[(n0+j)*256 + c] = fmaxf(y, 0.f);
        __syncthreads();
    }
}

extern "C" void kernel_launch(void* const* d_in, const int* in_sizes, int n_in,
                              void* d_out, int out_size, void* d_ws, size_t ws_size,
                              hipStream_t stream)
{
    const float* x        = (const float*)d_in[0];
    const int*   eidx     = (const int*)d_in[1];
    const float* etime    = (const float*)d_in[2];
    const float* eattr    = (const float*)d_in[3];
    const float* te_w1    = (const float*)d_in[4];
    const float* te_b1    = (const float*)d_in[5];
    const float* te_w2    = (const float*)d_in[6];
    const float* te_b2    = (const float*)d_in[7];
    const float* te_ln_g  = (const float*)d_in[8];
    const float* te_ln_b  = (const float*)d_in[9];
    const float* inp_w    = (const float*)d_in[10];
    const float* inp_b    = (const float*)d_in[11];
    const float* wq       = (const float*)d_in[12];
    const float* bq       = (const float*)d_in[13];
    const float* wk       = (const float*)d_in[14];
    const float* bk       = (const float*)d_in[15];
    const float* wv       = (const float*)d_in[16];
    const float* bv       = (const float*)d_in[17];
    const float* aow      = (const float*)d_in[18];
    const float* aob      = (const float*)d_in[19];
    const float* ow       = (const float*)d_in[20];
    const float* ob       = (const float*)d_in[21];
    const float* sc_w1    = (const float*)d_in[22];
    const float* sc_b1    = (const float*)d_in[23];
    const float* sc_w2    = (const float*)d_in[24];
    const float* sc_b2    = (const float*)d_in[25];
    const float* agg_w    = (const float*)d_in[26];
    const float* agg_b    = (const float*)d_in[27];
    const float* agg_g    = (const float*)d_in[28];
    const float* agg_bb   = (const float*)d_in[29];
    const float* decay    = (const float*)d_in[30];
    float* ws = (float*)d_ws;
    float* out = (float*)d_out;
    ushort* qb   = (ushort*)(ws + O_QB);
    ushort* kbuf = (ushort*)(ws + O_KB);
    ushort* vt   = (ushort*)(ws + O_VT);
    float4* recS = (float4*)(ws + O_RECS);
    float2* recT = (float2*)(ws + O_RECT);
    int* cnt_s   = (int*)(ws + O_CNTS);
    int* cnt_t   = (int*)(ws + O_CNTT);
    float* wtb   = ws + O_WT;
    float* comb  = ws + O_CMB;

    k_tr<<<640, 256, 0, stream>>>(inp_w, wq, wk, wv, aow, ow, sc_w1, agg_w, wtb,
                                  ws + O_CNTS);
    k_setup<<<33, 64, 0, stream>>>(te_w1, te_b1, te_w2, te_b2, te_ln_g, te_ln_b,
                                   sc_w1, ws+O_TAB, ws+O_AUX);
    k_proj_qkv<<<N_NODES/4, 256, 0, stream>>>(x, wtb, inp_b, bq, bk, bv, qb, kbuf, vt,
                                              ws+O_XSA, ws+O_XTB);
    k_ea<<<1536, 512, 0, stream>>>(qb, kbuf, vt, ws+O_CTXT,
                                   eidx, etime, eattr, ws+O_TAB, ws+O_AUX,
                                   sc_b1, sc_w2, sc_b2, decay,
                                   ws+O_XSA, ws+O_XTB,
                                   cnt_s, cnt_t, recS, recT);
    k_out_base<<<N_NODES/4, 256, 0, stream>>>(ws+O_CTXT, wtb, aob, ob, ws+O_BASE);
    k_gather<<<N_NODES, 256, 0, stream>>>(ws+O_BASE, recS, recT, cnt_s, cnt_t,
                                          ws+O_TAB, te_ln_b, comb);
    k_agg<<<N_NODES/4, 256, 0, stream>>>(comb, wtb, agg_b, agg_g, agg_bb, out);
}